// Round 1
// baseline (3698.646 us; speedup 1.0000x reference)
//
#include <hip/hip_runtime.h>

#define DIM 256
#define TM 128
#define TN 128
#define DK 32
#define NTHREADS 256

// ---------------- c2 kernel: c2h[k] = 0.5 * |codebook[k]|^2 ----------------
__global__ __launch_bounds__(256) void c2_kernel(const float* __restrict__ cb,
                                                 float* __restrict__ c2h, int K) {
    int w = (blockIdx.x * blockDim.x + threadIdx.x) >> 6;  // wave id = code id
    int lane = threadIdx.x & 63;
    if (w >= K) return;
    const float4 v = *(const float4*)(cb + (size_t)w * DIM + lane * 4);
    float s = v.x * v.x + v.y * v.y + v.z * v.z + v.w * v.w;
    #pragma unroll
    for (int off = 32; off > 0; off >>= 1) s += __shfl_down(s, off);
    if (lane == 0) c2h[w] = 0.5f * s;
}

// ---------------- main kernel ----------------
struct F4x4 { float4 v[4]; };

// Load one [128 rows] x [DK=32 d] chunk (1024 float4s, 4 per thread).
// d-fastest across lanes: 8 lanes cover one row's 128B -> coalesced.
__device__ __forceinline__ F4x4 load_tile(const float* __restrict__ base, int dk0, int t) {
    F4x4 r;
    #pragma unroll
    for (int l = 0; l < 4; ++l) {
        int i = t + l * NTHREADS;
        int row = i >> 3;
        int dd = (i & 7) << 2;
        r.v[l] = *(const float4*)(base + (size_t)row * DIM + dk0 + dd);
    }
    return r;
}

// Transposed store into LDS chunk S[DK][128] (d-major so compute reads are float4).
__device__ __forceinline__ void store_tile(float (*__restrict__ S)[TM], int t, const F4x4& r) {
    #pragma unroll
    for (int l = 0; l < 4; ++l) {
        int i = t + l * NTHREADS;
        int row = i >> 3;
        int dd = (i & 7) << 2;
        S[dd + 0][row] = r.v[l].x;
        S[dd + 1][row] = r.v[l].y;
        S[dd + 2][row] = r.v[l].z;
        S[dd + 3][row] = r.v[l].w;
    }
}

__global__ __launch_bounds__(NTHREADS, 2) void vq_kernel(
    const float* __restrict__ rep, const float* __restrict__ cb,
    const float* __restrict__ c2h, int* __restrict__ out, int N, int K) {
    __shared__ float As[2][DK][TM];
    __shared__ float Bs[2][DK][TN];

    const int t = threadIdx.x;
    const int tx = t & 15, ty = t >> 4;
    const int r0 = ty * 8, c0 = tx * 8;
    const int row0 = blockIdx.x * TM;
    if (row0 >= N) return;

    const float* __restrict__ abase = rep + (size_t)row0 * DIM;

    float best[8];
    int bidx[8];
    #pragma unroll
    for (int i = 0; i < 8; ++i) { best[i] = -3.4e38f; bidx[i] = 0; }

    for (int kt = 0; kt < K; kt += TN) {
        const float* __restrict__ bbase = cb + (size_t)kt * DIM;
        // prologue: stage chunk 0
        F4x4 ra = load_tile(abase, 0, t);
        F4x4 rb = load_tile(bbase, 0, t);
        // codebook half-norms for this tile (L1/L2-hot)
        float cc[8];
        *(float4*)&cc[0] = *(const float4*)(c2h + kt + c0);
        *(float4*)&cc[4] = *(const float4*)(c2h + kt + c0 + 4);
        store_tile(As[0], t, ra);
        store_tile(Bs[0], t, rb);
        __syncthreads();

        float acc[8][8] = {};

        #pragma unroll 1
        for (int dc = 0; dc < DIM / DK; ++dc) {
            const int cur = dc & 1;
            const bool more = (dc + 1 < DIM / DK);
            F4x4 na, nb;
            if (more) {
                na = load_tile(abase, (dc + 1) * DK, t);
                nb = load_tile(bbase, (dc + 1) * DK, t);
            }
            #pragma unroll 8
            for (int d = 0; d < DK; ++d) {
                float a[8], b[8];
                *(float4*)&a[0] = *(const float4*)&As[cur][d][r0];
                *(float4*)&a[4] = *(const float4*)&As[cur][d][r0 + 4];
                *(float4*)&b[0] = *(const float4*)&Bs[cur][d][c0];
                *(float4*)&b[4] = *(const float4*)&Bs[cur][d][c0 + 4];
                #pragma unroll
                for (int i = 0; i < 8; ++i)
                    #pragma unroll
                    for (int j = 0; j < 8; ++j)
                        acc[i][j] = fmaf(a[i], b[j], acc[i][j]);
            }
            if (more) {
                store_tile(As[cur ^ 1], t, na);
                store_tile(Bs[cur ^ 1], t, nb);
                __syncthreads();
            }
        }

        // fused argmin update: score = dot - 0.5|c|^2, argmax == argmin dist.
        // strict '>' + ascending code order == np.argmin first-min tie rule.
        #pragma unroll
        for (int j = 0; j < 8; ++j) {
            const float cj = cc[j];
            const int code = kt + c0 + j;
            #pragma unroll
            for (int i = 0; i < 8; ++i) {
                float s = acc[i][j] - cj;
                if (s > best[i]) { best[i] = s; bidx[i] = code; }
            }
        }
        __syncthreads();  // protect next tile's prologue stores
    }

    // cross-thread reduction: 16 tx threads share each row
    float* sv = &As[0][0][0];
    int* si = (int*)&Bs[0][0][0];
    #pragma unroll
    for (int i = 0; i < 8; ++i) {
        sv[(r0 + i) * 16 + tx] = best[i];
        si[(r0 + i) * 16 + tx] = bidx[i];
    }
    __syncthreads();
    if (t < TM) {
        float bv = sv[t * 16];
        int bi = si[t * 16];
        #pragma unroll
        for (int x = 1; x < 16; ++x) {
            float v = sv[t * 16 + x];
            int ii = si[t * 16 + x];
            if (v > bv || (v == bv && ii < bi)) { bv = v; bi = ii; }
        }
        out[row0 + t] = bi;
    }
}

extern "C" void kernel_launch(void* const* d_in, const int* in_sizes, int n_in,
                              void* d_out, int out_size, void* d_ws, size_t ws_size,
                              hipStream_t stream) {
    const float* rep = (const float*)d_in[0];
    const float* cb = (const float*)d_in[1];
    const int N = in_sizes[0] / DIM;  // 65536
    const int K = in_sizes[1] / DIM;  // 8192
    float* c2h = (float*)d_ws;        // K floats = 32 KB
    int* out = (int*)d_out;

    c2_kernel<<<dim3((K * 64 + 255) / 256), dim3(256), 0, stream>>>(cb, c2h, K);
    vq_kernel<<<dim3(N / TM), dim3(NTHREADS), 0, stream>>>(rep, cb, c2h, out, N, K);
}

// Round 3
// 1302.176 us; speedup vs baseline: 2.8404x; 2.8404x over previous
//
#include <hip/hip_runtime.h>

#define KCODES 8192
#define DIM 256
#define BM 128
#define BN 128
#define BK 32
#define NTHREADS 256
#define NCHUNK (DIM / BK)              // 8 d-chunks per kt tile
#define NQ ((KCODES / BN) * NCHUNK)    // 64 kt tiles * 8 = 512 steps

typedef _Float16 h16;
typedef __attribute__((ext_vector_type(8))) _Float16 f16x8;
typedef __attribute__((ext_vector_type(4))) float f32x4;

// ---------------- c2 kernel: c2h[k] = 0.5 * |codebook[k]|^2 ----------------
__global__ __launch_bounds__(256) void c2_kernel(const float* __restrict__ cb,
                                                 float* __restrict__ c2h, int K) {
    int w = (blockIdx.x * blockDim.x + threadIdx.x) >> 6;  // wave id = code id
    int lane = threadIdx.x & 63;
    if (w >= K) return;
    const float4 v = *(const float4*)(cb + (size_t)w * DIM + lane * 4);
    float s = v.x * v.x + v.y * v.y + v.z * v.z + v.w * v.w;
    #pragma unroll
    for (int off = 32; off > 0; off >>= 1) s += __shfl_down(s, off);
    if (lane == 0) c2h[w] = 0.5f * s;
}

// ---------------- main MFMA kernel ----------------
// LDS tile layout per operand: [row 0..127][128 bytes]; 8 16B-slots per row:
//   slots 0..3 = f16-high of d [s*8 .. s*8+7], slots 4..7 = f16-low residual.
// Swizzle (G4): phys_slot = s ^ (row & 7)  -> conflict-free b128 read & write.

__device__ __forceinline__ void split8(const float* __restrict__ x, f16x8& h, f16x8& l) {
    #pragma unroll
    for (int i = 0; i < 8; ++i) {
        float v = x[i];
        _Float16 hv = (_Float16)v;          // RNE
        h[i] = hv;
        l[i] = (_Float16)(v - (float)hv);   // exact residual in f32, RNE to f16
    }
}

__global__ __launch_bounds__(NTHREADS, 2) void vq_mfma(
    const float* __restrict__ rep, const float* __restrict__ cb,
    const float* __restrict__ c2h, int* __restrict__ out) {

    __shared__ __align__(16) h16 lds[2][2][BM * 64];  // [buf][A=0,B=1] = 64 KB

    const int t = threadIdx.x;
    const int lane = t & 63;
    const int w = t >> 6;                 // wave 0..3
    const int wrow = (w >> 1) * 64;       // wave's row block
    const int wcol = (w & 1) * 64;        // wave's col block
    const int row0 = blockIdx.x * BM;

    // staging mapping
    const int srow = t & 127;
    const int squad = t >> 7;             // 0 or 1

    // frag-read lane constants
    const int lrow_off = (lane & 15) * 64;
    const int g = lane >> 4;              // k-group 0..3

    f32x4 acc[4][4];
    float best[4][4];
    int bidx[4][4];
    #pragma unroll
    for (int m = 0; m < 4; ++m)
        #pragma unroll
        for (int n = 0; n < 4; ++n) {
            #pragma unroll
            for (int r = 0; r < 4; ++r) acc[m][n][r] = 0.f;
            best[m][n] = -3.4e38f;
            bidx[m][n] = 0;
        }

    float av[16], bv[16];
    auto load_globals = [&](int q) {
        const int kt = (q >> 3) * BN;
        const int dbase = (q & 7) * BK;
        const float* asrc = rep + (size_t)(row0 + srow) * DIM + dbase + squad * 16;
        const float* bsrc = cb + (size_t)(kt + srow) * DIM + dbase + squad * 16;
        #pragma unroll
        for (int i = 0; i < 4; ++i) *(float4*)&av[i * 4] = *(const float4*)(asrc + i * 4);
        #pragma unroll
        for (int i = 0; i < 4; ++i) *(float4*)&bv[i * 4] = *(const float4*)(bsrc + i * 4);
    };
    auto write_tile = [&](int buf) {
        h16* la = &lds[buf][0][0];
        h16* lb = &lds[buf][1][0];
        f16x8 hh, ll;
        #pragma unroll
        for (int half = 0; half < 2; ++half) {
            const int s = 2 * squad + half;
            const int ps_h = ((s) ^ (srow & 7)) << 3;
            const int ps_l = ((s + 4) ^ (srow & 7)) << 3;
            split8(&av[half * 8], hh, ll);
            *(f16x8*)&la[srow * 64 + ps_h] = hh;
            *(f16x8*)&la[srow * 64 + ps_l] = ll;
            split8(&bv[half * 8], hh, ll);
            *(f16x8*)&lb[srow * 64 + ps_h] = hh;
            *(f16x8*)&lb[srow * 64 + ps_l] = ll;
        }
    };

    load_globals(0);
    write_tile(0);
    __syncthreads();

    for (int q = 0; q < NQ; ++q) {
        const int cur = q & 1;
        const bool more = (q + 1 < NQ);
        if (more) load_globals(q + 1);   // issue early; consumed after MFMA

        const h16* la = &lds[cur][0][0];
        const h16* lb = &lds[cur][1][0];

        // ---- 4 split passes: h*h, h*l, l*h, l*l (full f16x2 product) ----
        f16x8 ah[4], bh[4], al[4], bl[4];
        #pragma unroll
        for (int m = 0; m < 4; ++m) {
            const int base = (wrow + m * 16) * 64 + lrow_off;
            ah[m] = *(const f16x8*)&la[base + ((g ^ (lane & 7)) << 3)];
            al[m] = *(const f16x8*)&la[base + (((4 + g) ^ (lane & 7)) << 3)];
        }
        #pragma unroll
        for (int n = 0; n < 4; ++n) {
            const int base = (wcol + n * 16) * 64 + lrow_off;
            bh[n] = *(const f16x8*)&lb[base + ((g ^ (lane & 7)) << 3)];
            bl[n] = *(const f16x8*)&lb[base + (((4 + g) ^ (lane & 7)) << 3)];
        }
        #pragma unroll
        for (int m = 0; m < 4; ++m)
            #pragma unroll
            for (int n = 0; n < 4; ++n)
                acc[m][n] = __builtin_amdgcn_mfma_f32_16x16x32_f16(ah[m], bh[n], acc[m][n], 0, 0, 0);
        #pragma unroll
        for (int m = 0; m < 4; ++m)
            #pragma unroll
            for (int n = 0; n < 4; ++n)
                acc[m][n] = __builtin_amdgcn_mfma_f32_16x16x32_f16(ah[m], bl[n], acc[m][n], 0, 0, 0);
        #pragma unroll
        for (int m = 0; m < 4; ++m)
            #pragma unroll
            for (int n = 0; n < 4; ++n)
                acc[m][n] = __builtin_amdgcn_mfma_f32_16x16x32_f16(al[m], bh[n], acc[m][n], 0, 0, 0);
        #pragma unroll
        for (int m = 0; m < 4; ++m)
            #pragma unroll
            for (int n = 0; n < 4; ++n)
                acc[m][n] = __builtin_amdgcn_mfma_f32_16x16x32_f16(al[m], bl[n], acc[m][n], 0, 0, 0);

        if (more) write_tile(cur ^ 1);

        // ---- per-kt argmin epilogue ----
        if ((q & 7) == 7) {
            const int ktbase = (q >> 3) * BN;
            #pragma unroll
            for (int n = 0; n < 4; ++n) {
                const int col = ktbase + wcol + n * 16 + (lane & 15);
                const float c2 = c2h[col];
                #pragma unroll
                for (int m = 0; m < 4; ++m)
                    #pragma unroll
                    for (int r = 0; r < 4; ++r) {
                        float s = acc[m][n][r] - c2;
                        if (s > best[m][r]) { best[m][r] = s; bidx[m][r] = col; }
                        acc[m][n][r] = 0.f;
                    }
            }
        }
        __syncthreads();
    }

    // ---- final reduce ----
    // Step 1: per-wave shfl reduce across the 16 col-lanes (tie -> lower idx).
    // Step 2: waves (2h, 2h+1) both cover rows [h*64, h*64+64) with disjoint
    //         col halves -> combine the two candidates through LDS scratch.
    float* sv = (float*)&lds[0][0][0];    // [row][whalf] 128*2 floats
    int* si = (int*)&lds[0][1][0];        // [row][whalf] 128*2 ints
    #pragma unroll
    for (int m = 0; m < 4; ++m)
        #pragma unroll
        for (int r = 0; r < 4; ++r) {
            float bv2 = best[m][r];
            int bi = bidx[m][r];
            #pragma unroll
            for (int mask = 1; mask <= 8; mask <<= 1) {
                float ov = __shfl_xor(bv2, mask);
                int oi = __shfl_xor(bi, mask);
                if (ov > bv2 || (ov == bv2 && oi < bi)) { bv2 = ov; bi = oi; }
            }
            if ((lane & 15) == 0) {
                const int rl = wrow + m * 16 + g * 4 + r;   // 0..127
                sv[rl * 2 + (w & 1)] = bv2;
                si[rl * 2 + (w & 1)] = bi;
            }
        }
    __syncthreads();
    if (t < BM) {
        float va = sv[t * 2 + 0], vb = sv[t * 2 + 1];
        int ia = si[t * 2 + 0], ib = si[t * 2 + 1];
        bool pickb = (vb > va) || (vb == va && ib < ia);
        out[row0 + t] = pickb ? ib : ia;
    }
}

extern "C" void kernel_launch(void* const* d_in, const int* in_sizes, int n_in,
                              void* d_out, int out_size, void* d_ws, size_t ws_size,
                              hipStream_t stream) {
    const float* rep = (const float*)d_in[0];
    const float* cb = (const float*)d_in[1];
    const int N = in_sizes[0] / DIM;   // 65536
    const int K = in_sizes[1] / DIM;   // 8192
    float* c2h = (float*)d_ws;         // K floats = 32 KB
    int* out = (int*)d_out;

    c2_kernel<<<dim3((K * 64 + 255) / 256), dim3(256), 0, stream>>>(cb, c2h, K);
    vq_mfma<<<dim3(N / BM), dim3(NTHREADS), 0, stream>>>(rep, cb, c2h, out);
}

// Round 4
// 1101.420 us; speedup vs baseline: 3.3581x; 1.1823x over previous
//
#include <hip/hip_runtime.h>

#define KCODES 8192
#define DIM 256
#define BM 64            // rows per block (4 waves x 16)
#define BN 128           // codebook cols per kt tile
#define NTHREADS 256
#define NKT (KCODES / BN)   // 64 tiles

typedef _Float16 h16;
typedef __attribute__((ext_vector_type(8))) _Float16 f16x8;
typedef __attribute__((ext_vector_type(4))) float f32x4;

// ---------------- c2 kernel: c2h[k] = 0.5 * |codebook[k]|^2 ----------------
__global__ __launch_bounds__(256) void c2_kernel(const float* __restrict__ cb,
                                                 float* __restrict__ c2h, int K) {
    int w = (blockIdx.x * blockDim.x + threadIdx.x) >> 6;  // wave id = code id
    int lane = threadIdx.x & 63;
    if (w >= K) return;
    const float4 v = *(const float4*)(cb + (size_t)w * DIM + lane * 4);
    float s = v.x * v.x + v.y * v.y + v.z * v.z + v.w * v.w;
    #pragma unroll
    for (int off = 32; off > 0; off >>= 1) s += __shfl_down(s, off);
    if (lane == 0) c2h[w] = 0.5f * s;
}

// ---------------- main MFMA kernel ----------------
// A (this block's 64 rep rows) lives PRE-SPLIT in registers for the whole
// kernel: per wave 16 rows, per lane 8 chunks x (h,l) f16x8 = 64 VGPR.
// Only B (codebook chunk, 128 cols x 32 d) streams through LDS, double-
// buffered, h|l f16 slots with XOR swizzle phys_slot = s ^ (col & 7).

__device__ __forceinline__ void split8(const float* __restrict__ x, f16x8& h, f16x8& l) {
    #pragma unroll
    for (int i = 0; i < 8; ++i) {
        float v = x[i];
        _Float16 hv = (_Float16)v;          // RNE
        h[i] = hv;
        l[i] = (_Float16)(v - (float)hv);   // exact residual in f32, RNE to f16
    }
}

__global__ __launch_bounds__(NTHREADS, 3) void vq_mfma(
    const float* __restrict__ rep, const float* __restrict__ cb,
    const float* __restrict__ c2h, int* __restrict__ out) {

    __shared__ __align__(16) h16 lds[2][BN * 64];   // 32 KB

    const int t = threadIdx.x;
    const int lane = t & 63;
    const int w = t >> 6;             // wave 0..3
    const int c15 = lane & 15;
    const int g = lane >> 4;          // k-group 0..3
    const int row0 = blockIdx.x * BM;
    const int wrow = w * 16;

    // ---- A fragments: load + split once ----
    f16x8 ah[8], al[8];
    {
        const float* ar = rep + (size_t)(row0 + wrow + c15) * DIM + g * 8;
        #pragma unroll
        for (int ch = 0; ch < 8; ++ch) {
            float x[8];
            *(float4*)&x[0] = *(const float4*)(ar + ch * 32);
            *(float4*)&x[4] = *(const float4*)(ar + ch * 32 + 4);
            split8(x, ah[ch], al[ch]);
        }
    }

    f32x4 acc[8];
    float best[4];
    int bidx[4];
    #pragma unroll
    for (int n = 0; n < 8; ++n)
        #pragma unroll
        for (int r = 0; r < 4; ++r) acc[n][r] = 0.f;
    #pragma unroll
    for (int r = 0; r < 4; ++r) { best[r] = -3.4e38f; bidx[r] = 0; }

    // ---- B staging: thread covers col (t>>1), d-halfwindow (t&1)*16 ----
    const int scol = t >> 1;
    const int dslot = t & 1;
    float breg[16];
    float cc[8];

    auto loadB = [&](int ktbase, int ch) {
        const float* src = cb + (size_t)(ktbase + scol) * DIM + ch * 32 + dslot * 16;
        #pragma unroll
        for (int i = 0; i < 4; ++i) *(float4*)&breg[i * 4] = *(const float4*)(src + i * 4);
    };
    auto writeB = [&](int buf) {
        #pragma unroll
        for (int half = 0; half < 2; ++half) {
            f16x8 hh, ll;
            split8(&breg[half * 8], hh, ll);
            const int s = dslot * 2 + half;
            *(f16x8*)&lds[buf][scol * 64 + ((s ^ (scol & 7)) << 3)] = hh;
            *(f16x8*)&lds[buf][scol * 64 + (((s + 4) ^ (scol & 7)) << 3)] = ll;
        }
    };

    // ---- prologue: buf0 <- chunk0, breg <- chunk1 ----
    loadB(0, 0);
    writeB(0);
    loadB(0, 1);
    __syncthreads();

    // ---- main loop: per step, write chunk+1 (from breg), issue chunk+2,
    //      compute chunk; one barrier per step ----
    for (int kt = 0; kt < NKT; ++kt) {
        const int ktbase = kt * BN;
        #pragma unroll
        for (int chunk = 0; chunk < 8; ++chunk) {
            const int buf = chunk & 1;                       // compile-time
            // (1) convert previous loads (chunk+1 data) into the other buffer
            if (!(chunk == 7 && kt == NKT - 1)) writeB(buf ^ 1);
            // (2) issue global loads for chunk+2
            if (chunk <= 5) loadB(ktbase, chunk + 2);
            else if (kt + 1 < NKT) loadB(ktbase + BN, chunk - 6);
            // (3) per-kt codebook half-norms
            if (chunk == 0) {
                #pragma unroll
                for (int n = 0; n < 8; ++n) cc[n] = c2h[ktbase + n * 16 + c15];
            }
            // (4) compute: 8 n-frags x 4 split passes (hh, hl, lh, ll)
            #pragma unroll
            for (int n = 0; n < 8; ++n) {
                const int base = (n * 16 + c15) * 64;
                f16x8 bh = *(const f16x8*)&lds[buf][base + ((g ^ (lane & 7)) << 3)];
                f16x8 bl = *(const f16x8*)&lds[buf][base + (((4 + g) ^ (lane & 7)) << 3)];
                acc[n] = __builtin_amdgcn_mfma_f32_16x16x32_f16(ah[chunk], bh, acc[n], 0, 0, 0);
                acc[n] = __builtin_amdgcn_mfma_f32_16x16x32_f16(ah[chunk], bl, acc[n], 0, 0, 0);
                acc[n] = __builtin_amdgcn_mfma_f32_16x16x32_f16(al[chunk], bh, acc[n], 0, 0, 0);
                acc[n] = __builtin_amdgcn_mfma_f32_16x16x32_f16(al[chunk], bl, acc[n], 0, 0, 0);
            }
            // (5) per-kt argmin epilogue (strict '>' + ascending order = np tie rule)
            if (chunk == 7) {
                #pragma unroll
                for (int n = 0; n < 8; ++n) {
                    const int col = ktbase + n * 16 + c15;
                    #pragma unroll
                    for (int r = 0; r < 4; ++r) {
                        float s2 = acc[n][r] - cc[n];
                        if (s2 > best[r]) { best[r] = s2; bidx[r] = col; }
                        acc[n][r] = 0.f;
                    }
                }
            }
            __syncthreads();
        }
    }

    // ---- final reduce: rows are wave-exclusive; reduce across the 16
    //      col-lanes within each k-group (tie -> lower index) ----
    #pragma unroll
    for (int r = 0; r < 4; ++r) {
        float bv = best[r];
        int bi = bidx[r];
        #pragma unroll
        for (int mask = 1; mask <= 8; mask <<= 1) {
            float ov = __shfl_xor(bv, mask);
            int oi = __shfl_xor(bi, mask);
            if (ov > bv || (ov == bv && oi < bi)) { bv = ov; bi = oi; }
        }
        if (c15 == 0) out[row0 + wrow + g * 4 + r] = bi;
    }
}

extern "C" void kernel_launch(void* const* d_in, const int* in_sizes, int n_in,
                              void* d_out, int out_size, void* d_ws, size_t ws_size,
                              hipStream_t stream) {
    const float* rep = (const float*)d_in[0];
    const float* cb = (const float*)d_in[1];
    const int N = in_sizes[0] / DIM;   // 65536
    const int K = in_sizes[1] / DIM;   // 8192
    float* c2h = (float*)d_ws;         // K floats = 32 KB
    int* out = (int*)d_out;

    c2_kernel<<<dim3((K * 64 + 255) / 256), dim3(256), 0, stream>>>(cb, c2h, K);
    vq_mfma<<<dim3(N / BM), dim3(NTHREADS), 0, stream>>>(rep, cb, c2h, out);
}

// Round 5
// 861.960 us; speedup vs baseline: 4.2910x; 1.2778x over previous
//
#include <hip/hip_runtime.h>
#include <stdint.h>

#define KCODES 8192
#define DIM 256
#define BM 64            // rows per block (4 waves x 16)
#define BN 128           // codebook cols per kt tile
#define NTHREADS 256
#define NKT (KCODES / BN)   // 64 tiles
#define NQ (NKT * 8)        // 512 chunk-steps

typedef _Float16 h16;
typedef __attribute__((ext_vector_type(8))) _Float16 f16x8;
typedef __attribute__((ext_vector_type(4))) float f32x4;

__device__ __forceinline__ void split8(const float* __restrict__ x, f16x8& h, f16x8& l) {
    #pragma unroll
    for (int i = 0; i < 8; ++i) {
        float v = x[i];
        _Float16 hv = (_Float16)v;          // RNE
        h[i] = hv;
        l[i] = (_Float16)(v - (float)hv);   // exact residual in f32, RNE to f16
    }
}

// ---------------- c2 kernel: c2h[k] = 0.5 * |codebook[k]|^2 ----------------
__global__ __launch_bounds__(256) void c2_kernel(const float* __restrict__ cb,
                                                 float* __restrict__ c2h, int K) {
    int w = (blockIdx.x * blockDim.x + threadIdx.x) >> 6;
    int lane = threadIdx.x & 63;
    if (w >= K) return;
    const float4 v = *(const float4*)(cb + (size_t)w * DIM + lane * 4);
    float s = v.x * v.x + v.y * v.y + v.z * v.z + v.w * v.w;
    #pragma unroll
    for (int off = 32; off > 0; off >>= 1) s += __shfl_down(s, off);
    if (lane == 0) c2h[w] = 0.5f * s;
}

// ---------------- pack kernel: codebook -> pre-split, pre-swizzled image ----
// Bp is 512 chunk-blocks of 16 KB. Chunk-block (kt*8+chunk) holds, at h16
// offset col*64 + p*8 (p = phys 16B slot), the data the main kernel expects
// at the same LINEAR LDS offset:  s = p ^ (col&7); s<4 -> f16-high of
// d [chunk*32 + s*8 .. +7] of code kt*128+col; s>=4 -> f16-low residual.
__global__ __launch_bounds__(256) void pack_kernel(const float* __restrict__ cb,
                                                   h16* __restrict__ Bp) {
    const int tid = blockIdx.x * 256 + threadIdx.x;   // 8192*32 threads
    const int code = tid >> 5;
    const int grp = tid & 31;                         // 8-d group
    float x[8];
    *(float4*)&x[0] = *(const float4*)(cb + (size_t)code * DIM + grp * 8);
    *(float4*)&x[4] = *(const float4*)(cb + (size_t)code * DIM + grp * 8 + 4);
    f16x8 hh, ll;
    split8(x, hh, ll);
    const int kt = code >> 7, col = code & 127;
    const int chunk = grp >> 2, s = grp & 3;
    const int ph = s ^ (col & 7), pl = (s + 4) ^ (col & 7);
    h16* base = Bp + ((size_t)(kt * 8 + chunk) * 8192) + col * 64;
    *(f16x8*)(base + ph * 8) = hh;
    *(f16x8*)(base + pl * 8) = ll;
}

// ---------------- main MFMA kernel (fast path) ----------------
// A (block's 64 rep rows) pre-split in registers (16 f16x8/lane).
// B streams through a 3-deep LDS ring via global_load_lds (no VGPR trip,
// no ds_writes), counted vmcnt keeps 2 chunks in flight across barriers.
__global__ __launch_bounds__(NTHREADS, 3) void vq_mfma_pk(
    const float* __restrict__ rep, const h16* __restrict__ Bp,
    const float* __restrict__ c2h, int* __restrict__ out) {

    __shared__ __align__(16) h16 ring[3][8192];   // 48 KB

    const int t = threadIdx.x;
    const int lane = t & 63;
    const int c15 = lane & 15;
    const int g = lane >> 4;          // k-group 0..3
    const int w = t >> 6;
    const int row0 = blockIdx.x * BM;
    const int wrow = w * 16;

    // ---- A fragments: load + split once ----
    f16x8 ah[8], al[8];
    {
        const float* ar = rep + (size_t)(row0 + wrow + c15) * DIM + g * 8;
        #pragma unroll
        for (int ch = 0; ch < 8; ++ch) {
            float x[8];
            *(float4*)&x[0] = *(const float4*)(ar + ch * 32);
            *(float4*)&x[4] = *(const float4*)(ar + ch * 32 + 4);
            split8(x, ah[ch], al[ch]);
        }
    }

    f32x4 acc[8];
    float best[4], cc[8];
    int bidx[4];
    #pragma unroll
    for (int n = 0; n < 8; ++n)
        #pragma unroll
        for (int r = 0; r < 4; ++r) acc[n][r] = 0.f;
    #pragma unroll
    for (int r = 0; r < 4; ++r) { best[r] = -3.4e38f; bidx[r] = 0; }

    auto issueB = [&](int q2, int slot) {
        const h16* src = Bp + (size_t)q2 * 8192 + t * 8;
        h16* dst = &ring[slot][t * 8];
        #pragma unroll
        for (int i = 0; i < 4; ++i)
            __builtin_amdgcn_global_load_lds(
                (const __attribute__((address_space(1))) uint32_t*)(src + i * 2048),
                (__attribute__((address_space(3))) uint32_t*)(dst + i * 2048),
                16, 0, 0);
    };

    // drain prologue A-loads so vmcnt counting below is exact
    asm volatile("s_waitcnt vmcnt(0)" ::: "memory");
    issueB(0, 0);
    issueB(1, 1);

    int bufq = 0;
    #pragma unroll 1
    for (int kt = 0; kt < NKT; ++kt) {
        const int ktbase = kt * BN;
        #pragma unroll
        for (int chunk = 0; chunk < 8; ++chunk) {
            const int q = kt * 8 + chunk;
            // chunk q's loads were issued 2 steps ago; newest 4 outstanding
            // are chunk q+1's -> vmcnt(4) guarantees q landed. lgkmcnt(0)
            // drains my ds_reads before the rendezvous (overwrite hazard).
            if (q == NQ - 1) asm volatile("s_waitcnt vmcnt(0) lgkmcnt(0)" ::: "memory");
            else             asm volatile("s_waitcnt vmcnt(4) lgkmcnt(0)" ::: "memory");
            __builtin_amdgcn_s_barrier();
            __builtin_amdgcn_sched_barrier(0);   // rule 18: nothing crosses the barrier

            if (q + 2 < NQ) {
                int slot = bufq + 2;
                if (slot >= 3) slot -= 3;
                issueB(q + 2, slot);
            }
            if (chunk == 0) {
                #pragma unroll
                for (int n = 0; n < 8; ++n) cc[n] = c2h[ktbase + n * 16 + c15];
            }

            const h16* lb = &ring[bufq][0];
            #pragma unroll
            for (int n = 0; n < 8; ++n) {
                const int base = (n * 16 + c15) * 64;
                f16x8 bh = *(const f16x8*)&lb[base + ((g ^ (lane & 7)) << 3)];
                f16x8 bl = *(const f16x8*)&lb[base + (((4 + g) ^ (lane & 7)) << 3)];
                acc[n] = __builtin_amdgcn_mfma_f32_16x16x32_f16(ah[chunk], bh, acc[n], 0, 0, 0);
                acc[n] = __builtin_amdgcn_mfma_f32_16x16x32_f16(ah[chunk], bl, acc[n], 0, 0, 0);
                acc[n] = __builtin_amdgcn_mfma_f32_16x16x32_f16(al[chunk], bh, acc[n], 0, 0, 0);
                acc[n] = __builtin_amdgcn_mfma_f32_16x16x32_f16(al[chunk], bl, acc[n], 0, 0, 0);
            }

            if (chunk == 7) {   // per-kt argmin epilogue (strict '>' = np tie rule)
                #pragma unroll
                for (int n = 0; n < 8; ++n) {
                    const int col = ktbase + n * 16 + c15;
                    #pragma unroll
                    for (int r = 0; r < 4; ++r) {
                        float s2 = acc[n][r] - cc[n];
                        if (s2 > best[r]) { best[r] = s2; bidx[r] = col; }
                        acc[n][r] = 0.f;
                    }
                }
            }
            bufq = (bufq + 1 == 3) ? 0 : bufq + 1;
        }
    }

    // ---- final reduce: rows wave-exclusive; shfl across the 16 col-lanes ----
    #pragma unroll
    for (int r = 0; r < 4; ++r) {
        float bv = best[r];
        int bi = bidx[r];
        #pragma unroll
        for (int mask = 1; mask <= 8; mask <<= 1) {
            float ov = __shfl_xor(bv, mask);
            int oi = __shfl_xor(bi, mask);
            if (ov > bv || (ov == bv && oi < bi)) { bv = ov; bi = oi; }
        }
        if (c15 == 0) out[row0 + wrow + g * 4 + r] = bi;
    }
}

// ---------------- fallback (R4 kernel, in-loop split) for small ws ----------
__global__ __launch_bounds__(NTHREADS, 3) void vq_mfma_fb(
    const float* __restrict__ rep, const float* __restrict__ cb,
    const float* __restrict__ c2h, int* __restrict__ out) {

    __shared__ __align__(16) h16 lds[2][BN * 64];

    const int t = threadIdx.x;
    const int lane = t & 63;
    const int w = t >> 6;
    const int c15 = lane & 15;
    const int g = lane >> 4;
    const int row0 = blockIdx.x * BM;
    const int wrow = w * 16;

    f16x8 ah[8], al[8];
    {
        const float* ar = rep + (size_t)(row0 + wrow + c15) * DIM + g * 8;
        #pragma unroll
        for (int ch = 0; ch < 8; ++ch) {
            float x[8];
            *(float4*)&x[0] = *(const float4*)(ar + ch * 32);
            *(float4*)&x[4] = *(const float4*)(ar + ch * 32 + 4);
            split8(x, ah[ch], al[ch]);
        }
    }

    f32x4 acc[8];
    float best[4];
    int bidx[4];
    #pragma unroll
    for (int n = 0; n < 8; ++n)
        #pragma unroll
        for (int r = 0; r < 4; ++r) acc[n][r] = 0.f;
    #pragma unroll
    for (int r = 0; r < 4; ++r) { best[r] = -3.4e38f; bidx[r] = 0; }

    const int scol = t >> 1;
    const int dslot = t & 1;
    float breg[16];
    float cc[8];

    auto loadB = [&](int ktbase, int ch) {
        const float* src = cb + (size_t)(ktbase + scol) * DIM + ch * 32 + dslot * 16;
        #pragma unroll
        for (int i = 0; i < 4; ++i) *(float4*)&breg[i * 4] = *(const float4*)(src + i * 4);
    };
    auto writeB = [&](int buf) {
        #pragma unroll
        for (int half = 0; half < 2; ++half) {
            f16x8 hh, ll;
            split8(&breg[half * 8], hh, ll);
            const int s = dslot * 2 + half;
            *(f16x8*)&lds[buf][scol * 64 + ((s ^ (scol & 7)) << 3)] = hh;
            *(f16x8*)&lds[buf][scol * 64 + (((s + 4) ^ (scol & 7)) << 3)] = ll;
        }
    };

    loadB(0, 0);
    writeB(0);
    loadB(0, 1);
    __syncthreads();

    for (int kt = 0; kt < NKT; ++kt) {
        const int ktbase = kt * BN;
        #pragma unroll
        for (int chunk = 0; chunk < 8; ++chunk) {
            const int buf = chunk & 1;
            if (!(chunk == 7 && kt == NKT - 1)) writeB(buf ^ 1);
            if (chunk <= 5) loadB(ktbase, chunk + 2);
            else if (kt + 1 < NKT) loadB(ktbase + BN, chunk - 6);
            if (chunk == 0) {
                #pragma unroll
                for (int n = 0; n < 8; ++n) cc[n] = c2h[ktbase + n * 16 + c15];
            }
            #pragma unroll
            for (int n = 0; n < 8; ++n) {
                const int base = (n * 16 + c15) * 64;
                f16x8 bh = *(const f16x8*)&lds[buf][base + ((g ^ (lane & 7)) << 3)];
                f16x8 bl = *(const f16x8*)&lds[buf][base + (((4 + g) ^ (lane & 7)) << 3)];
                acc[n] = __builtin_amdgcn_mfma_f32_16x16x32_f16(ah[chunk], bh, acc[n], 0, 0, 0);
                acc[n] = __builtin_amdgcn_mfma_f32_16x16x32_f16(ah[chunk], bl, acc[n], 0, 0, 0);
                acc[n] = __builtin_amdgcn_mfma_f32_16x16x32_f16(al[chunk], bh, acc[n], 0, 0, 0);
                acc[n] = __builtin_amdgcn_mfma_f32_16x16x32_f16(al[chunk], bl, acc[n], 0, 0, 0);
            }
            if (chunk == 7) {
                #pragma unroll
                for (int n = 0; n < 8; ++n) {
                    const int col = ktbase + n * 16 + c15;
                    #pragma unroll
                    for (int r = 0; r < 4; ++r) {
                        float s2 = acc[n][r] - cc[n];
                        if (s2 > best[r]) { best[r] = s2; bidx[r] = col; }
                        acc[n][r] = 0.f;
                    }
                }
            }
            __syncthreads();
        }
    }

    #pragma unroll
    for (int r = 0; r < 4; ++r) {
        float bv = best[r];
        int bi = bidx[r];
        #pragma unroll
        for (int mask = 1; mask <= 8; mask <<= 1) {
            float ov = __shfl_xor(bv, mask);
            int oi = __shfl_xor(bi, mask);
            if (ov > bv || (ov == bv && oi < bi)) { bv = ov; bi = oi; }
        }
        if (c15 == 0) out[row0 + wrow + g * 4 + r] = bi;
    }
}

extern "C" void kernel_launch(void* const* d_in, const int* in_sizes, int n_in,
                              void* d_out, int out_size, void* d_ws, size_t ws_size,
                              hipStream_t stream) {
    const float* rep = (const float*)d_in[0];
    const float* cb = (const float*)d_in[1];
    const int N = in_sizes[0] / DIM;   // 65536
    const int K = in_sizes[1] / DIM;   // 8192
    float* c2h = (float*)d_ws;         // 32 KB
    int* out = (int*)d_out;
    const size_t need = (size_t)32768 + (size_t)KCODES * DIM * 2 * sizeof(h16);  // 8.4 MB

    c2_kernel<<<dim3((K * 64 + 255) / 256), dim3(256), 0, stream>>>(cb, c2h, K);
    if (ws_size >= need) {
        h16* Bp = (h16*)((char*)d_ws + 32768);
        pack_kernel<<<dim3(KCODES * 32 / 256), dim3(256), 0, stream>>>(cb, Bp);
        vq_mfma_pk<<<dim3(N / BM), dim3(NTHREADS), 0, stream>>>(rep, Bp, c2h, out);
    } else {
        vq_mfma_fb<<<dim3(N / BM), dim3(NTHREADS), 0, stream>>>(rep, cb, c2h, out);
    }
}

// Round 6
// 681.535 us; speedup vs baseline: 5.4269x; 1.2647x over previous
//
#include <hip/hip_runtime.h>
#include <stdint.h>

#define KCODES 8192
#define DIM 256
#define BM 64            // rows per block; waves: 2 row-halves x 2 col-halves
#define BN 128           // codebook cols per kt tile
#define NTHREADS 256
#define NKT (KCODES / BN)   // 64 tiles
#define NQ (NKT * 8)        // 512 chunk-steps

typedef _Float16 h16;
typedef __attribute__((ext_vector_type(8))) _Float16 f16x8;
typedef __attribute__((ext_vector_type(4))) float f32x4;

__device__ __forceinline__ void split8(const float* __restrict__ x, f16x8& h, f16x8& l) {
    #pragma unroll
    for (int i = 0; i < 8; ++i) {
        float v = x[i];
        _Float16 hv = (_Float16)v;          // RNE
        h[i] = hv;
        l[i] = (_Float16)(v - (float)hv);   // exact residual in f32, RNE to f16
    }
}

// ---------------- c2 kernel: c2h[k] = 0.5 * |codebook[k]|^2 ----------------
__global__ __launch_bounds__(256) void c2_kernel(const float* __restrict__ cb,
                                                 float* __restrict__ c2h, int K) {
    int w = (blockIdx.x * blockDim.x + threadIdx.x) >> 6;
    int lane = threadIdx.x & 63;
    if (w >= K) return;
    const float4 v = *(const float4*)(cb + (size_t)w * DIM + lane * 4);
    float s = v.x * v.x + v.y * v.y + v.z * v.z + v.w * v.w;
    #pragma unroll
    for (int off = 32; off > 0; off >>= 1) s += __shfl_down(s, off);
    if (lane == 0) c2h[w] = 0.5f * s;
}

// ---------------- pack kernel: codebook -> pre-split, pre-swizzled image ----
// 512 chunk-blocks of 16 KB; chunk-block (kt*8+chunk) at h16 offset
// col*64 + p*8 holds: s = p ^ (col&7); s<4 -> f16-high of d [chunk*32+s*8..+7]
// of code kt*128+col; s>=4 -> f16-low residual.
__global__ __launch_bounds__(256) void pack_kernel(const float* __restrict__ cb,
                                                   h16* __restrict__ Bp) {
    const int tid = blockIdx.x * 256 + threadIdx.x;
    const int code = tid >> 5;
    const int grp = tid & 31;
    float x[8];
    *(float4*)&x[0] = *(const float4*)(cb + (size_t)code * DIM + grp * 8);
    *(float4*)&x[4] = *(const float4*)(cb + (size_t)code * DIM + grp * 8 + 4);
    f16x8 hh, ll;
    split8(x, hh, ll);
    const int kt = code >> 7, col = code & 127;
    const int chunk = grp >> 2, s = grp & 3;
    const int ph = s ^ (col & 7), pl = (s + 4) ^ (col & 7);
    h16* base = Bp + ((size_t)(kt * 8 + chunk) * 8192) + col * 64;
    *(f16x8*)(base + ph * 8) = hh;
    *(f16x8*)(base + pl * 8) = ll;
}

// ---------------- main MFMA kernel ----------------
// Wave tile 32 rows x 64 cols (2m x 4n of 16x16x32). A pre-split in regs
// (128 VGPR). B streams via global_load_lds into a 3-deep ring; counted
// vmcnt(4) keeps prefetch in flight across barriers. 3-pass split product
// (hh + hl + lh; ll term ~1e-6 << top-2 gaps ~1e-2).
__global__ __launch_bounds__(NTHREADS, 2) void vq_mfma_pk(
    const float* __restrict__ rep, const h16* __restrict__ Bp,
    const float* __restrict__ c2h, int* __restrict__ out) {

    __shared__ __align__(16) h16 ring[3][8192];   // 48 KB

    const int t = threadIdx.x;
    const int lane = t & 63;
    const int c15 = lane & 15;
    const int g = lane >> 4;              // k-group 0..3
    const int w = t >> 6;
    const int wrow = (w >> 1) * 32;       // row half: waves {0,1}->0, {2,3}->32
    const int wcol = (w & 1) * 64;        // col half: waves {0,2}->0, {1,3}->64
    const int row0 = blockIdx.x * BM;

    // ---- A fragments: 2 row-subtiles x 8 chunks, load + split once ----
    f16x8 ah[2][8], al[2][8];
    #pragma unroll
    for (int m = 0; m < 2; ++m) {
        const float* ar = rep + (size_t)(row0 + wrow + m * 16 + c15) * DIM + g * 8;
        #pragma unroll
        for (int ch = 0; ch < 8; ++ch) {
            float x[8];
            *(float4*)&x[0] = *(const float4*)(ar + ch * 32);
            *(float4*)&x[4] = *(const float4*)(ar + ch * 32 + 4);
            split8(x, ah[m][ch], al[m][ch]);
        }
    }

    f32x4 acc[2][4];
    float best[2][4], cc[4];
    int bidx[2][4];
    #pragma unroll
    for (int m = 0; m < 2; ++m)
        #pragma unroll
        for (int n = 0; n < 4; ++n)
            #pragma unroll
            for (int r = 0; r < 4; ++r) acc[m][n][r] = 0.f;
    #pragma unroll
    for (int m = 0; m < 2; ++m)
        #pragma unroll
        for (int r = 0; r < 4; ++r) { best[m][r] = -3.4e38f; bidx[m][r] = 0; }

    auto issueB = [&](int q2, int slot) {
        const h16* src = Bp + (size_t)q2 * 8192 + t * 8;
        h16* dst = &ring[slot][t * 8];
        #pragma unroll
        for (int i = 0; i < 4; ++i)
            __builtin_amdgcn_global_load_lds(
                (const __attribute__((address_space(1))) uint32_t*)(src + i * 2048),
                (__attribute__((address_space(3))) uint32_t*)(dst + i * 2048),
                16, 0, 0);
    };

    // drain prologue A-loads so vmcnt counting below is exact
    asm volatile("s_waitcnt vmcnt(0)" ::: "memory");
    issueB(0, 0);
    issueB(1, 1);

    int bufq = 0;
    #pragma unroll 1
    for (int kt = 0; kt < NKT; ++kt) {
        const int ktbase = kt * BN;
        #pragma unroll
        for (int chunk = 0; chunk < 8; ++chunk) {
            const int q = kt * 8 + chunk;
            // q's loads issued 2 steps ago; newest 4 outstanding are q+1's
            // prefetch -> vmcnt(4) proves q landed. lgkmcnt(0) drains my
            // ds_reads before the rendezvous (ring-slot overwrite hazard).
            if (q == NQ - 1) asm volatile("s_waitcnt vmcnt(0) lgkmcnt(0)" ::: "memory");
            else             asm volatile("s_waitcnt vmcnt(4) lgkmcnt(0)" ::: "memory");
            __builtin_amdgcn_s_barrier();
            __builtin_amdgcn_sched_barrier(0);   // rule 18: nothing crosses

            // cc BEFORE issueB so the newest 4 vmcnt entries stay the prefetch
            if (chunk == 0) {
                #pragma unroll
                for (int n = 0; n < 4; ++n) cc[n] = c2h[ktbase + wcol + n * 16 + c15];
            }
            if (q + 2 < NQ) {
                int slot = bufq + 2;
                if (slot >= 3) slot -= 3;
                issueB(q + 2, slot);
            }

            const h16* lb = &ring[bufq][0];
            #pragma unroll
            for (int n = 0; n < 4; ++n) {
                const int base = (wcol + n * 16 + c15) * 64;
                f16x8 bh = *(const f16x8*)&lb[base + ((g ^ (lane & 7)) << 3)];
                f16x8 bl = *(const f16x8*)&lb[base + (((4 + g) ^ (lane & 7)) << 3)];
                #pragma unroll
                for (int m = 0; m < 2; ++m) {
                    acc[m][n] = __builtin_amdgcn_mfma_f32_16x16x32_f16(ah[m][chunk], bh, acc[m][n], 0, 0, 0);
                    acc[m][n] = __builtin_amdgcn_mfma_f32_16x16x32_f16(ah[m][chunk], bl, acc[m][n], 0, 0, 0);
                    acc[m][n] = __builtin_amdgcn_mfma_f32_16x16x32_f16(al[m][chunk], bh, acc[m][n], 0, 0, 0);
                }
            }

            if (chunk == 7) {   // per-kt argmin epilogue (strict '>' = np tie rule)
                #pragma unroll
                for (int n = 0; n < 4; ++n) {
                    const int col = ktbase + wcol + n * 16 + c15;
                    #pragma unroll
                    for (int m = 0; m < 2; ++m)
                        #pragma unroll
                        for (int r = 0; r < 4; ++r) {
                            float s2 = acc[m][n][r] - cc[n];
                            if (s2 > best[m][r]) { best[m][r] = s2; bidx[m][r] = col; }
                            acc[m][n][r] = 0.f;
                        }
                }
            }
            bufq = (bufq + 1 == 3) ? 0 : bufq + 1;
        }
    }

    // ---- final reduce ----
    // Step 1: shfl across the 16 col-lanes (tie -> lower idx).
    // Step 2: two col-half waves cover each row -> combine via LDS scratch.
    // ring[0] is safe scratch: last compute step (q=511) reads ring[1] only,
    // and every wave drained lgkmcnt before the q=511 barrier.
    float* sv = (float*)&ring[0][0];      // [row 0..63][half 0..1]
    int* si = (int*)&ring[0][1024];
    #pragma unroll
    for (int m = 0; m < 2; ++m)
        #pragma unroll
        for (int r = 0; r < 4; ++r) {
            float bv = best[m][r];
            int bi = bidx[m][r];
            #pragma unroll
            for (int mask = 1; mask <= 8; mask <<= 1) {
                float ov = __shfl_xor(bv, mask);
                int oi = __shfl_xor(bi, mask);
                if (ov > bv || (ov == bv && oi < bi)) { bv = ov; bi = oi; }
            }
            if (c15 == 0) {
                const int rl = wrow + m * 16 + g * 4 + r;   // 0..63
                sv[rl * 2 + (w & 1)] = bv;
                si[rl * 2 + (w & 1)] = bi;
            }
        }
    __syncthreads();
    if (t < BM) {
        float va = sv[t * 2 + 0], vb = sv[t * 2 + 1];
        int ia = si[t * 2 + 0], ib = si[t * 2 + 1];
        bool pickb = (vb > va) || (vb == va && ib < ia);
        out[row0 + t] = pickb ? ib : ia;
    }
}

extern "C" void kernel_launch(void* const* d_in, const int* in_sizes, int n_in,
                              void* d_out, int out_size, void* d_ws, size_t ws_size,
                              hipStream_t stream) {
    const float* rep = (const float*)d_in[0];
    const float* cb = (const float*)d_in[1];
    const int N = in_sizes[0] / DIM;   // 65536
    const int K = in_sizes[1] / DIM;   // 8192
    float* c2h = (float*)d_ws;         // 32 KB
    h16* Bp = (h16*)((char*)d_ws + 32768);   // 8 MB (ws >= 8.4 MB, proven R5)
    int* out = (int*)d_out;

    c2_kernel<<<dim3((K * 64 + 255) / 256), dim3(256), 0, stream>>>(cb, c2h, K);
    pack_kernel<<<dim3(KCODES * 32 / 256), dim3(256), 0, stream>>>(cb, Bp);
    vq_mfma_pk<<<dim3(N / BM), dim3(NTHREADS), 0, stream>>>(rep, Bp, c2h, out);
}